// Round 2
// baseline (202.496 us; speedup 1.0000x reference)
//
#include <hip/hip_runtime.h>

typedef __attribute__((ext_vector_type(8))) short bf16x8;
typedef __attribute__((ext_vector_type(4))) float f32x4;

#define HW_ (128 * 128)

__device__ __forceinline__ unsigned short f2bf(float f) {
  unsigned int u = __builtin_bit_cast(unsigned int, f);
  u += 0x7fffu + ((u >> 16) & 1u);
  return (unsigned short)(u >> 16);
}

// weight (64,64,3,3) f32 -> wb[p][o][c] bf16 (36864 elems, 73728 B in d_ws)
__global__ __launch_bounds__(256) void prep_w(const float* __restrict__ w,
                                              unsigned short* __restrict__ wb) {
  int t = blockIdx.x * 256 + threadIdx.x;  // < 36864
  int p = t >> 12;
  int rem = t & 4095;
  int o = rem >> 6, c = rem & 63;
  wb[t] = f2bf(w[(o * 64 + c) * 9 + p]);
}

// Band kernel: block = (b, w-half 64 cols, 4 output rows). 256 thr / 4 waves.
// x rolling 4 slots [66 cols][64 c] bf16 (swizzled), guide rolling 3 slots
// [66 cols][20 cg-pad] f32 (transposed), klds [9][64] f32. Weights in VGPRs.
__global__ __launch_bounds__(256, 2) void pac_main(
    const float* __restrict__ x, const float* __restrict__ g,
    const unsigned short* __restrict__ wb, const float* __restrict__ bias,
    float* __restrict__ out) {
  __shared__ unsigned short xs[4 * 66 * 64];  // 33792 B
  __shared__ float gs[3 * 66 * 20];           // 15840 B
  __shared__ float klds[9 * 64];              // 2304 B

  const int tid = threadIdx.x;
  const int w0 = blockIdx.x * 64;
  const int h0 = blockIdx.y * 4;
  const int b = blockIdx.z;
  const int l = tid & 63;
  const int wv = tid >> 6;
  const int wave_m = wv & 1, wave_n = wv >> 1;
  const int l15 = l & 15, lhi = l >> 4;

  // ---------- staging lambdas (issue = global->reg, commit = reg->LDS) ----
  auto x_issue = [&](int t, f32x4* plo, f32x4* phi, float* ph) {
    const bool vh = (unsigned)t < 128u;
#pragma unroll
    for (int ti = 0; ti < 2; ++ti) {
      int e = tid + ti * 256;        // e < 512 : c = e>>3, octet gq = e&7
      int c = e >> 3, gq = e & 7;
      const float* p =
          x + (((size_t)(b * 64 + c)) * 128 + (vh ? t : 0)) * 128 + w0 + gq * 8;
      f32x4 lo = {0.f, 0.f, 0.f, 0.f}, hi = {0.f, 0.f, 0.f, 0.f};
      if (vh) {
        lo = *reinterpret_cast<const f32x4*>(p);
        hi = *reinterpret_cast<const f32x4*>(p + 4);
      }
      plo[ti] = lo;
      phi[ti] = hi;
    }
    float hv = 0.f;
    if (tid < 128) {
      int c = tid >> 1, side = tid & 1;
      int gw = w0 - 1 + side * 65;
      bool ok = vh && ((unsigned)gw < 128u);
      if (ok) hv = x[(((size_t)(b * 64 + c)) * 128 + t) * 128 + gw];
    }
    *ph = hv;
  };
  auto x_commit = [&](int slot, const f32x4* plo, const f32x4* phi, float ph) {
    const int base = slot * (66 * 64);
#pragma unroll
    for (int ti = 0; ti < 2; ++ti) {
      int e = tid + ti * 256;
      int c = e >> 3, gq = e & 7;
      float v[8];
#pragma unroll
      for (int u = 0; u < 4; ++u) {
        v[u] = plo[ti][u];
        v[u + 4] = phi[ti][u];
      }
#pragma unroll
      for (int k = 0; k < 8; ++k) {
        int col = gq * 8 + 1 + k;
        int sw = (col ^ (col >> 3)) & 7;
        xs[base + (col << 6) + ((((c >> 3) ^ sw)) << 3) + (c & 7)] = f2bf(v[k]);
      }
    }
    if (tid < 128) {
      int c = tid >> 1, side = tid & 1;
      int col = side * 65;
      int sw = (col ^ (col >> 3)) & 7;
      xs[base + (col << 6) + ((((c >> 3) ^ sw)) << 3) + (c & 7)] = f2bf(ph);
    }
  };
  auto g_issue = [&](int t, float* pg) {
    const bool vh = (unsigned)t < 128u;
#pragma unroll
    for (int i = 0; i < 5; ++i) {
      int e = tid + i * 256;
      float v = 0.f;
      if (e < 1056) {
        int cg = e / 66, col = e - cg * 66;
        int gw = w0 - 1 + col;
        if (vh && (unsigned)gw < 128u)
          v = g[(((size_t)(b * 16 + cg)) * 128 + t) * 128 + gw];
      }
      pg[i] = v;
    }
  };
  auto g_commit = [&](int gsI, const float* pg) {
#pragma unroll
    for (int i = 0; i < 5; ++i) {
      int e = tid + i * 256;
      if (e < 1056) {
        int cg = e / 66, col = e - cg * 66;
        gs[gsI * (66 * 20) + col * 20 + cg] = pg[i];
      }
    }
  };

  // ---------- kern: klds[p][m] for row h0+r (r compile-time) ---------------
  auto kern_row = [&](int r) {
    const int m = tid >> 2, q = tid & 3;
    f32x4 win[3][3];
#pragma unroll
    for (int di = 0; di < 3; ++di) {
      const int gsI = (r + di) % 3;
#pragma unroll
      for (int dc = 0; dc < 3; ++dc)
        win[di][dc] = *reinterpret_cast<const f32x4*>(
            &gs[gsI * (66 * 20) + (m + dc) * 20 + q * 4]);
    }
#pragma unroll
    for (int di = 0; di < 3; ++di)
#pragma unroll
      for (int dj = 0; dj < 3; ++dj) {
        f32x4 d = win[di][dj] - win[1][1];
        float s = d[0] * d[0] + d[1] * d[1] + d[2] * d[2] + d[3] * d[3];
        s += __shfl_xor(s, 1, 64);
        s += __shfl_xor(s, 2, 64);
        if (q == 0) klds[(di * 3 + dj) * 64 + m] = __expf(-0.5f * s);
      }
  };

  // ---------- weights -> registers (36 frags = 144 VGPR) -------------------
  bf16x8 wfr[9][2][2];
#pragma unroll
  for (int p = 0; p < 9; ++p)
#pragma unroll
    for (int kk = 0; kk < 2; ++kk)
#pragma unroll
      for (int fr = 0; fr < 2; ++fr)
        wfr[p][kk][fr] = *reinterpret_cast<const bf16x8*>(
            &wb[(p * 64 + wave_n * 32 + fr * 16 + l15) * 64 + kk * 32 +
                lhi * 8]);
  float bv[2][4];
#pragma unroll
  for (int fr = 0; fr < 2; ++fr)
#pragma unroll
    for (int j = 0; j < 4; ++j)
      bv[fr][j] = bias[wave_n * 32 + fr * 16 + lhi * 4 + j];

  // x fragment offsets within a slot (shorts): 12 values, loop-invariant
  int xoff[3][2][2];
#pragma unroll
  for (int dj = 0; dj < 3; ++dj)
#pragma unroll
    for (int fc = 0; fc < 2; ++fc) {
      int col = wave_m * 32 + fc * 16 + l15 + dj;
      int sw = (col ^ (col >> 3)) & 7;
#pragma unroll
      for (int kk = 0; kk < 2; ++kk)
        xoff[dj][fc][kk] = (col << 6) + (((kk * 4 + lhi) ^ sw) << 3);
    }

  // ---------- MFMA + epilogue for row h0+r --------------------------------
  auto mfma_row = [&](int r) {
    const int h = h0 + r;
    f32x4 acc[2][2];
#pragma unroll
    for (int i = 0; i < 2; ++i)
#pragma unroll
      for (int j = 0; j < 2; ++j) acc[i][j] = (f32x4){0.f, 0.f, 0.f, 0.f};
#pragma unroll
    for (int di = 0; di < 3; ++di) {
      const int slot = (r + di) & 3;
      const int sbase = slot * (66 * 64);
#pragma unroll
      for (int dj = 0; dj < 3; ++dj) {
        const int p = di * 3 + dj;
        f32x4 tmp[2][2];
#pragma unroll
        for (int i = 0; i < 2; ++i)
#pragma unroll
          for (int j = 0; j < 2; ++j) tmp[i][j] = (f32x4){0.f, 0.f, 0.f, 0.f};
#pragma unroll
        for (int kk = 0; kk < 2; ++kk) {
          bf16x8 xf0 = *reinterpret_cast<const bf16x8*>(
              &xs[sbase + xoff[dj][0][kk]]);
          bf16x8 xf1 = *reinterpret_cast<const bf16x8*>(
              &xs[sbase + xoff[dj][1][kk]]);
#pragma unroll
          for (int fr = 0; fr < 2; ++fr) {
            tmp[fr][0] = __builtin_amdgcn_mfma_f32_16x16x32_bf16(
                wfr[p][kk][fr], xf0, tmp[fr][0], 0, 0, 0);
            tmp[fr][1] = __builtin_amdgcn_mfma_f32_16x16x32_bf16(
                wfr[p][kk][fr], xf1, tmp[fr][1], 0, 0, 0);
          }
        }
        const float km0 = klds[p * 64 + wave_m * 32 + l15];
        const float km1 = klds[p * 64 + wave_m * 32 + 16 + l15];
#pragma unroll
        for (int fr = 0; fr < 2; ++fr)
#pragma unroll
          for (int j = 0; j < 4; ++j) {
            acc[fr][0][j] += km0 * tmp[fr][0][j];
            acc[fr][1][j] += km1 * tmp[fr][1][j];
          }
      }
    }
#pragma unroll
    for (int fr = 0; fr < 2; ++fr)
#pragma unroll
      for (int j = 0; j < 4; ++j) {
        const int o = wave_n * 32 + fr * 16 + lhi * 4 + j;
#pragma unroll
        for (int fc = 0; fc < 2; ++fc) {
          const int m = wave_m * 32 + fc * 16 + l15;
          float v = acc[fr][fc][j] + bv[fr][j];
          out[(((size_t)(b * 64 + o)) * 128 + h) * 128 + w0 + m] =
              v > 0.f ? v : 0.f;
        }
      }
  };

  // ---------- prologue: rows h0-1, h0, h0+1 -> slots 0,1,2 -----------------
  f32x4 alo[2], ahi[2];
  float ah, ag[5];
  f32x4 blo[2], bhi[2];
  float bh, bg[5];
  x_issue(h0 - 1, alo, ahi, &ah);
  g_issue(h0 - 1, ag);
  x_issue(h0, blo, bhi, &bh);
  g_issue(h0, bg);
  x_commit(0, alo, ahi, ah);
  g_commit(0, ag);
  x_issue(h0 + 1, alo, ahi, &ah);
  g_issue(h0 + 1, ag);
  x_commit(1, blo, bhi, bh);
  g_commit(1, bg);
  x_commit(2, alo, ahi, ah);
  g_commit(2, ag);
  __syncthreads();

  // ---------- main loop: 4 rows, fully unrolled ---------------------------
#pragma unroll
  for (int r = 0; r < 4; ++r) {
    if (r < 3) {  // prefetch row h0+r+2 (issue loads early)
      x_issue(h0 + r + 2, alo, ahi, &ah);
      g_issue(h0 + r + 2, ag);
    }
    kern_row(r);
    __syncthreads();
    mfma_row(r);
    if (r < 3) {  // commit staged row: x slot (r+3)&3, guide slot r%3
      x_commit((r + 3) & 3, alo, ahi, ah);
      g_commit(r % 3, ag);
    }
    __syncthreads();
  }
}

extern "C" void kernel_launch(void* const* d_in, const int* in_sizes, int n_in,
                              void* d_out, int out_size, void* d_ws, size_t ws_size,
                              hipStream_t stream) {
  const float* x = (const float*)d_in[0];
  const float* guide = (const float*)d_in[1];
  const float* weight = (const float*)d_in[2];
  const float* bias = (const float*)d_in[3];
  float* out = (float*)d_out;
  unsigned short* wb = (unsigned short*)d_ws;  // 73728 bytes

  hipLaunchKernelGGL(prep_w, dim3(36864 / 256), dim3(256), 0, stream, weight, wb);
  hipLaunchKernelGGL(pac_main, dim3(2, 32, 8), dim3(256), 0, stream,
                     x, guide, wb, bias, out);
}

// Round 3
// 160.407 us; speedup vs baseline: 1.2624x; 1.2624x over previous
//
#include <hip/hip_runtime.h>

typedef __attribute__((ext_vector_type(8))) short bf16x8;
typedef __attribute__((ext_vector_type(4))) float f32x4;
typedef __attribute__((ext_vector_type(8))) unsigned short u16x8;
typedef __attribute__((ext_vector_type(4))) unsigned short u16x4;

__device__ __forceinline__ unsigned short f2bf(float f) {
  unsigned int u = __builtin_bit_cast(unsigned int, f);
  u += 0x7fffu + ((u >> 16) & 1u);
  return (unsigned short)(u >> 16);
}
__device__ __forceinline__ float bf2f(unsigned short h) {
  unsigned int u = ((unsigned int)h) << 16;
  return __builtin_bit_cast(float, u);
}

// weight (64,64,3,3) f32 -> wb[p][o][c] bf16 (36864 elems, 73728 B in d_ws)
__global__ __launch_bounds__(256) void prep_w(const float* __restrict__ w,
                                              unsigned short* __restrict__ wb) {
  int t = blockIdx.x * 256 + threadIdx.x;  // < 36864
  int p = t >> 12;
  int rem = t & 4095;
  int o = rem >> 6, c = rem & 63;
  wb[t] = f2bf(w[(o * 64 + c) * 9 + p]);
}

// Block = (b, 4-row band, FULL 128-col width). 512 thr / 8 waves, 1 block/CU.
// xs: 4 rolling slots [130 col][64 ch] bf16, XOR-swizzled. gs: 3 slots
// [130 col][16 cg] bf16. klds [9][128] f32. Weights resident in VGPRs.
__global__ __launch_bounds__(512, 2) void pac_main(
    const float* __restrict__ x, const float* __restrict__ gin,
    const unsigned short* __restrict__ wb, const float* __restrict__ bias,
    float* __restrict__ out) {
  __shared__ unsigned short xs[4 * 130 * 64];  // 66560 B
  __shared__ unsigned short gs[3 * 130 * 16];  // 12480 B
  __shared__ float klds[9 * 128];              // 4608 B

  const int tid = threadIdx.x;
  const int bid = blockIdx.x;
  const int b = bid & 7;          // all 32 bands of batch b land on one XCD
  const int h0 = (bid >> 3) * 4;
  const int l = tid & 63;
  const int wv = tid >> 6;
  const int l15 = l & 15, lhi = l >> 4;
  const int oh = wv & 1, mq = wv >> 1;  // wave tile: o 32-half x m 32-quarter

  // ---- zero boundary cols (0 and 129) of all slots, once ----
  if (tid < 64) {
    int slot = tid >> 4, which = (tid >> 3) & 1, co = tid & 7;
    int col = which ? 129 : 0;
    u16x8 z = {0, 0, 0, 0, 0, 0, 0, 0};
    *reinterpret_cast<u16x8*>(
        &xs[slot * 8320 + col * 64 + ((co ^ (col & 7)) << 3)]) = z;
  }
  if (tid < 12) {
    int slot = tid >> 2, which = (tid >> 1) & 1, cgo = tid & 1;
    int col = which ? 129 : 0;
    u16x8 z = {0, 0, 0, 0, 0, 0, 0, 0};
    *reinterpret_cast<u16x8*>(&gs[slot * 2080 + col * 16 + cgo * 8]) = z;
  }

  // ---- staging: waves 0-3 stage x, waves 4-7 stage guide ----
  f32x4 xv[8];
  float gv[8];
  auto issue = [&](int t) {
    const int row = h0 + t;
    const bool vh = (unsigned)row < 128u;
    if (tid < 256) {
      const int co = tid >> 5, wq = tid & 31;
      const float* p =
          x + (((size_t)(b * 64 + co * 8)) * 128 + (vh ? row : 0)) * 128 + wq * 4;
#pragma unroll
      for (int u = 0; u < 8; ++u) {
        f32x4 v = {0.f, 0.f, 0.f, 0.f};
        if (vh) v = *reinterpret_cast<const f32x4*>(p + (size_t)u * 16384);
        xv[u] = v;
      }
    } else {
      const int u2 = tid - 256, cgo = u2 >> 7, w = u2 & 127;
      const float* p =
          gin + (((size_t)(b * 16 + cgo * 8)) * 128 + (vh ? row : 0)) * 128 + w;
#pragma unroll
      for (int q = 0; q < 8; ++q) {
        float v = 0.f;
        if (vh) v = p[(size_t)q * 16384];
        gv[q] = v;
      }
    }
  };
  auto commit = [&](int xslot, int gslot) {
    if (tid < 256) {
      const int co = tid >> 5, wq = tid & 31;
#pragma unroll
      for (int j = 0; j < 4; ++j) {
        const int col = wq * 4 + j + 1;
        unsigned short t8[8];
#pragma unroll
        for (int u = 0; u < 8; ++u) t8[u] = f2bf(xv[u][j]);
        *reinterpret_cast<u16x8*>(
            &xs[xslot * 8320 + col * 64 + ((co ^ (col & 7)) << 3)]) =
            *reinterpret_cast<const u16x8*>(t8);
      }
    } else {
      const int u2 = tid - 256, cgo = u2 >> 7, w = u2 & 127;
      unsigned short t8[8];
#pragma unroll
      for (int q = 0; q < 8; ++q) t8[q] = f2bf(gv[q]);
      *reinterpret_cast<u16x8*>(&gs[gslot * 2080 + (w + 1) * 16 + cgo * 8]) =
          *reinterpret_cast<const u16x8*>(t8);
    }
  };

  // ---- weights -> registers (36 frags = 144 VGPR), pinned live ----
  bf16x8 wfr[9][2][2];
#pragma unroll
  for (int p = 0; p < 9; ++p)
#pragma unroll
    for (int kk = 0; kk < 2; ++kk)
#pragma unroll
      for (int fr = 0; fr < 2; ++fr) {
        wfr[p][kk][fr] = *reinterpret_cast<const bf16x8*>(
            &wb[(p * 64 + oh * 32 + fr * 16 + l15) * 64 + kk * 32 + lhi * 8]);
        asm volatile("" ::"v"(wfr[p][kk][fr]));
      }
  float bv[2][4];
#pragma unroll
  for (int fr = 0; fr < 2; ++fr)
#pragma unroll
    for (int j = 0; j < 4; ++j)
      bv[fr][j] = bias[oh * 32 + fr * 16 + lhi * 4 + j];

  // x fragment short-offsets within a slot (compile-time-indexed)
  int xoff[3][2][2];
#pragma unroll
  for (int dj = 0; dj < 3; ++dj)
#pragma unroll
    for (int fc = 0; fc < 2; ++fc) {
      const int col = mq * 32 + fc * 16 + l15 + dj;
#pragma unroll
      for (int kk = 0; kk < 2; ++kk)
        xoff[dj][fc][kk] = col * 64 + (((kk * 4 + lhi) ^ (col & 7)) << 3);
    }

  // ---- bilateral kernel for output row h0+r (all 512 threads, 4/pixel) ----
  auto kern_row = [&](int r) {
    const int m = tid >> 2, q = tid & 3;
    float wf[3][3][4];
#pragma unroll
    for (int di = 0; di < 3; ++di) {
      const int sl = ((r + di + 2) % 3) * 2080;
#pragma unroll
      for (int dc = 0; dc < 3; ++dc) {
        u16x4 v = *reinterpret_cast<const u16x4*>(&gs[sl + (m + dc) * 16 + q * 4]);
#pragma unroll
        for (int e = 0; e < 4; ++e) wf[di][dc][e] = bf2f(v[e]);
      }
    }
#pragma unroll
    for (int di = 0; di < 3; ++di)
#pragma unroll
      for (int dj = 0; dj < 3; ++dj) {
        float s = 0.f;
#pragma unroll
        for (int e = 0; e < 4; ++e) {
          float d = wf[di][dj][e] - wf[1][1][e];
          s += d * d;
        }
        s += __shfl_xor(s, 1, 64);
        s += __shfl_xor(s, 2, 64);
        if (q == 0) klds[(di * 3 + dj) * 128 + m] = __expf(-0.5f * s);
      }
  };

  // ---- MFMA + epilogue for output row h0+r ----
  auto mfma_row = [&](int r) {
    const int h = h0 + r;
    f32x4 acc[2][2];
#pragma unroll
    for (int i = 0; i < 2; ++i)
#pragma unroll
      for (int j = 0; j < 2; ++j) acc[i][j] = (f32x4){0.f, 0.f, 0.f, 0.f};
#pragma unroll
    for (int di = 0; di < 3; ++di) {
      const int sbase = ((r + di) & 3) * 8320;
#pragma unroll
      for (int dj = 0; dj < 3; ++dj) {
        const int p = di * 3 + dj;
        f32x4 tmp[2][2];
#pragma unroll
        for (int i = 0; i < 2; ++i)
#pragma unroll
          for (int j = 0; j < 2; ++j) tmp[i][j] = (f32x4){0.f, 0.f, 0.f, 0.f};
#pragma unroll
        for (int kk = 0; kk < 2; ++kk) {
          bf16x8 xf0 =
              *reinterpret_cast<const bf16x8*>(&xs[sbase + xoff[dj][0][kk]]);
          bf16x8 xf1 =
              *reinterpret_cast<const bf16x8*>(&xs[sbase + xoff[dj][1][kk]]);
#pragma unroll
          for (int fr = 0; fr < 2; ++fr) {
            tmp[fr][0] = __builtin_amdgcn_mfma_f32_16x16x32_bf16(
                wfr[p][kk][fr], xf0, tmp[fr][0], 0, 0, 0);
            tmp[fr][1] = __builtin_amdgcn_mfma_f32_16x16x32_bf16(
                wfr[p][kk][fr], xf1, tmp[fr][1], 0, 0, 0);
          }
        }
        const float km0 = klds[p * 128 + mq * 32 + l15];
        const float km1 = klds[p * 128 + mq * 32 + 16 + l15];
#pragma unroll
        for (int fr = 0; fr < 2; ++fr)
#pragma unroll
          for (int j = 0; j < 4; ++j) {
            acc[fr][0][j] += km0 * tmp[fr][0][j];
            acc[fr][1][j] += km1 * tmp[fr][1][j];
          }
      }
    }
#pragma unroll
    for (int fr = 0; fr < 2; ++fr)
#pragma unroll
      for (int j = 0; j < 4; ++j) {
        const int o = oh * 32 + fr * 16 + lhi * 4 + j;
        float* rp = out + (((size_t)(b * 64 + o)) * 128 + h) * 128;
#pragma unroll
        for (int fc = 0; fc < 2; ++fc) {
          float v = acc[fr][fc][j] + bv[fr][j];
          rp[mq * 32 + fc * 16 + l15] = v > 0.f ? v : 0.f;
        }
      }
  };

  // ---- prologue: rows -1,0,1 -> x slots 0,1,2 / g slots 2,0,1 ----
  issue(-1);
  commit(0, 2);
  issue(0);
  commit(1, 0);
  issue(1);
  commit(2, 1);
  __syncthreads();

  // ---- main loop ----
#pragma unroll
  for (int r = 0; r < 4; ++r) {
    if (r < 3) issue(r + 2);  // loads in flight across kern + mfma
    kern_row(r);
    __syncthreads();
    mfma_row(r);
    if (r < 3) commit((r + 3) & 3, (r + 2) % 3);
    __syncthreads();
  }
}

extern "C" void kernel_launch(void* const* d_in, const int* in_sizes, int n_in,
                              void* d_out, int out_size, void* d_ws, size_t ws_size,
                              hipStream_t stream) {
  const float* x = (const float*)d_in[0];
  const float* guide = (const float*)d_in[1];
  const float* weight = (const float*)d_in[2];
  const float* bias = (const float*)d_in[3];
  float* out = (float*)d_out;
  unsigned short* wb = (unsigned short*)d_ws;  // 73728 bytes

  hipLaunchKernelGGL(prep_w, dim3(36864 / 256), dim3(256), 0, stream, weight, wb);
  hipLaunchKernelGGL(pac_main, dim3(256), dim3(512), 0, stream,
                     x, guide, wb, bias, out);
}

// Round 6
// 120.266 us; speedup vs baseline: 1.6837x; 1.3338x over previous
//
#include <hip/hip_runtime.h>

typedef __attribute__((ext_vector_type(8))) short bf16x8;
typedef __attribute__((ext_vector_type(4))) float f32x4;
typedef __attribute__((ext_vector_type(8))) unsigned short u16x8;
typedef __attribute__((ext_vector_type(4))) unsigned short u16x4;

__device__ __forceinline__ unsigned short f2bf(float f) {
  unsigned int u = __builtin_bit_cast(unsigned int, f);
  u += 0x7fffu + ((u >> 16) & 1u);
  return (unsigned short)(u >> 16);
}
__device__ __forceinline__ float bf2f(unsigned short h) {
  unsigned int u = ((unsigned int)h) << 16;
  return __builtin_bit_cast(float, u);
}

// weight (64,64,3,3) f32 -> wb[p][o][c] bf16 (36864 elems, 73728 B in d_ws)
__global__ __launch_bounds__(256) void prep_w(const float* __restrict__ w,
                                              unsigned short* __restrict__ wb) {
  int t = blockIdx.x * 256 + threadIdx.x;  // < 36864
  int p = t >> 12;
  int rem = t & 4095;
  int o = rem >> 6, c = rem & 63;
  wb[t] = f2bf(w[(o * 64 + c) * 9 + p]);
}

// Block = (b, 4-row band, FULL 128-col width). 512 thr / 8 waves, 1 block/CU.
// xs: 4 rolling slots [130 col][64 ch] bf16, XOR-swizzled. gs: 3 slots
// [130 col][16 cg] bf16. klds [9][128] f32. Weights in LDS (swizzled).
__global__ __launch_bounds__(512, 2) void pac_main(
    const float* __restrict__ x, const float* __restrict__ gin,
    const unsigned short* __restrict__ wb, const float* __restrict__ bias,
    float* __restrict__ out) {
  __shared__ unsigned short xs[4 * 130 * 64];   // 66560 B
  __shared__ unsigned short gs[3 * 130 * 16];   // 12480 B
  __shared__ float klds[9 * 128];               // 4608 B
  __shared__ unsigned short wlds[9 * 64 * 64];  // 73728 B

  const int tid = threadIdx.x;
  const int bid = blockIdx.x;
  const int b = bid & 7;          // all 32 bands of batch b land on one XCD
  const int h0 = (bid >> 3) * 4;
  const int l = tid & 63;
  const int wv = tid >> 6;
  const int l15 = l & 15, lhi = l >> 4;
  const int oh = wv & 1, mq = wv >> 1;  // wave tile: o 32-half x m 32-quarter

  // ---- stage weights wb[p][o][c] -> wlds swizzled (9 x u16x8 per thread) ---
#pragma unroll
  for (int i = 0; i < 9; ++i) {
    int e8 = i * 512 + tid;           // chunk index < 4608
    int p = e8 >> 9, o = (e8 >> 3) & 63, ch = e8 & 7;
    u16x8 v = *reinterpret_cast<const u16x8*>(&wb[e8 * 8]);
    *reinterpret_cast<u16x8*>(
        &wlds[(p * 64 + o) * 64 + ((ch ^ (o & 7)) << 3)]) = v;
  }

  // ---- zero boundary cols (0 and 129) of all slots, once ----
  if (tid < 64) {
    int slot = tid >> 4, which = (tid >> 3) & 1, co = tid & 7;
    int col = which ? 129 : 0;
    u16x8 z = {0, 0, 0, 0, 0, 0, 0, 0};
    *reinterpret_cast<u16x8*>(
        &xs[slot * 8320 + col * 64 + ((co ^ (col & 7)) << 3)]) = z;
  }
  if (tid < 12) {
    int slot = tid >> 2, which = (tid >> 1) & 1, cgo = tid & 1;
    int col = which ? 129 : 0;
    u16x8 z = {0, 0, 0, 0, 0, 0, 0, 0};
    *reinterpret_cast<u16x8*>(&gs[slot * 2080 + col * 16 + cgo * 8]) = z;
  }

  // ---- staging: waves 0-3 stage x, waves 4-7 stage guide ----
  f32x4 xv[8];
  float gv[8];
  auto issue = [&](int t) {
    const int row = h0 + t;
    const bool vh = (unsigned)row < 128u;
    if (tid < 256) {
      const int co = tid >> 5, wq = tid & 31;
      const float* p =
          x + (((size_t)(b * 64 + co * 8)) * 128 + (vh ? row : 0)) * 128 + wq * 4;
#pragma unroll
      for (int u = 0; u < 8; ++u) {
        f32x4 v = {0.f, 0.f, 0.f, 0.f};
        if (vh) v = *reinterpret_cast<const f32x4*>(p + (size_t)u * 16384);
        xv[u] = v;
      }
    } else {
      const int u2 = tid - 256, cgo = u2 >> 7, w = u2 & 127;
      const float* p =
          gin + (((size_t)(b * 16 + cgo * 8)) * 128 + (vh ? row : 0)) * 128 + w;
#pragma unroll
      for (int q = 0; q < 8; ++q) {
        float v = 0.f;
        if (vh) v = p[(size_t)q * 16384];
        gv[q] = v;
      }
    }
  };
  auto commit = [&](int xslot, int gslot) {
    if (tid < 256) {
      const int co = tid >> 5, wq = tid & 31;
#pragma unroll
      for (int j = 0; j < 4; ++j) {
        const int col = wq * 4 + j + 1;
        unsigned short t8[8];
#pragma unroll
        for (int u = 0; u < 8; ++u) t8[u] = f2bf(xv[u][j]);
        *reinterpret_cast<u16x8*>(
            &xs[xslot * 8320 + col * 64 + ((co ^ (col & 7)) << 3)]) =
            *reinterpret_cast<const u16x8*>(t8);
      }
    } else {
      const int u2 = tid - 256, cgo = u2 >> 7, w = u2 & 127;
      unsigned short t8[8];
#pragma unroll
      for (int q = 0; q < 8; ++q) t8[q] = f2bf(gv[q]);
      *reinterpret_cast<u16x8*>(&gs[gslot * 2080 + (w + 1) * 16 + cgo * 8]) =
          *reinterpret_cast<const u16x8*>(t8);
    }
  };

  float bv[2][4];
#pragma unroll
  for (int fr = 0; fr < 2; ++fr)
#pragma unroll
    for (int j = 0; j < 4; ++j)
      bv[fr][j] = bias[oh * 32 + fr * 16 + lhi * 4 + j];

  // x fragment short-offsets within a slot (compile-time-indexed)
  int xoff[3][2][2];
#pragma unroll
  for (int dj = 0; dj < 3; ++dj)
#pragma unroll
    for (int fc = 0; fc < 2; ++fc) {
      const int col = mq * 32 + fc * 16 + l15 + dj;
#pragma unroll
      for (int kk = 0; kk < 2; ++kk)
        xoff[dj][fc][kk] = col * 64 + (((kk * 4 + lhi) ^ (col & 7)) << 3);
    }

  // ---- bilateral kernel for output row h0+r (all 512 threads, 4/pixel) ----
  auto kern_row = [&](int r) {
    const int m = tid >> 2, q = tid & 3;
    float wf[3][3][4];
#pragma unroll
    for (int di = 0; di < 3; ++di) {
      const int sl = ((r + di + 2) % 3) * 2080;
#pragma unroll
      for (int dc = 0; dc < 3; ++dc) {
        u16x4 v = *reinterpret_cast<const u16x4*>(&gs[sl + (m + dc) * 16 + q * 4]);
#pragma unroll
        for (int e = 0; e < 4; ++e) wf[di][dc][e] = bf2f(v[e]);
      }
    }
#pragma unroll
    for (int di = 0; di < 3; ++di)
#pragma unroll
      for (int dj = 0; dj < 3; ++dj) {
        float s = 0.f;
#pragma unroll
        for (int e = 0; e < 4; ++e) {
          float d = wf[di][dj][e] - wf[1][1][e];
          s += d * d;
        }
        s += __shfl_xor(s, 1, 64);
        s += __shfl_xor(s, 2, 64);
        if (q == 0) klds[(di * 3 + dj) * 128 + m] = __expf(-0.5f * s);
      }
  };

  // ---- MFMA + epilogue for output row h0+r ----
  auto mfma_row = [&](int r) {
    const int h = h0 + r;
    const int aswz = l15 & 7;
    f32x4 acc[2][2];
#pragma unroll
    for (int i = 0; i < 2; ++i)
#pragma unroll
      for (int j = 0; j < 2; ++j) acc[i][j] = (f32x4){0.f, 0.f, 0.f, 0.f};
#pragma unroll
    for (int di = 0; di < 3; ++di) {
      const int sbase = ((r + di) & 3) * 8320;
#pragma unroll
      for (int dj = 0; dj < 3; ++dj) {
        const int p = di * 3 + dj;
        f32x4 tmp[2][2];
#pragma unroll
        for (int i = 0; i < 2; ++i)
#pragma unroll
          for (int j = 0; j < 2; ++j) tmp[i][j] = (f32x4){0.f, 0.f, 0.f, 0.f};
        bf16x8 af[2][2];
#pragma unroll
        for (int kk = 0; kk < 2; ++kk)
#pragma unroll
          for (int fr = 0; fr < 2; ++fr) {
            const int o = oh * 32 + fr * 16 + l15;
            af[kk][fr] = *reinterpret_cast<const bf16x8*>(
                &wlds[(p * 64 + o) * 64 + (((kk * 4 + lhi) ^ aswz) << 3)]);
          }
#pragma unroll
        for (int kk = 0; kk < 2; ++kk) {
          bf16x8 xf0 =
              *reinterpret_cast<const bf16x8*>(&xs[sbase + xoff[dj][0][kk]]);
          bf16x8 xf1 =
              *reinterpret_cast<const bf16x8*>(&xs[sbase + xoff[dj][1][kk]]);
#pragma unroll
          for (int fr = 0; fr < 2; ++fr) {
            tmp[fr][0] = __builtin_amdgcn_mfma_f32_16x16x32_bf16(
                af[kk][fr], xf0, tmp[fr][0], 0, 0, 0);
            tmp[fr][1] = __builtin_amdgcn_mfma_f32_16x16x32_bf16(
                af[kk][fr], xf1, tmp[fr][1], 0, 0, 0);
          }
        }
        const float km0 = klds[p * 128 + mq * 32 + l15];
        const float km1 = klds[p * 128 + mq * 32 + 16 + l15];
#pragma unroll
        for (int fr = 0; fr < 2; ++fr)
#pragma unroll
          for (int j = 0; j < 4; ++j) {
            acc[fr][0][j] += km0 * tmp[fr][0][j];
            acc[fr][1][j] += km1 * tmp[fr][1][j];
          }
      }
    }
#pragma unroll
    for (int fr = 0; fr < 2; ++fr)
#pragma unroll
      for (int j = 0; j < 4; ++j) {
        const int o = oh * 32 + fr * 16 + lhi * 4 + j;
        float* rp = out + (((size_t)(b * 64 + o)) * 128 + h) * 128;
#pragma unroll
        for (int fc = 0; fc < 2; ++fc) {
          float v = acc[fr][fc][j] + bv[fr][j];
          __builtin_nontemporal_store(v > 0.f ? v : 0.f,
                                      &rp[mq * 32 + fc * 16 + l15]);
        }
      }
  };

  // ---- prologue: rows -1,0,1 -> x slots 0,1,2 / g slots 2,0,1 ----
  issue(-1);
  commit(0, 2);
  issue(0);
  commit(1, 0);
  issue(1);
  commit(2, 1);
  __syncthreads();

  // ---- main loop ----
#pragma unroll
  for (int r = 0; r < 4; ++r) {
    if (r < 3) issue(r + 2);  // loads in flight across kern + mfma
    kern_row(r);
    __syncthreads();
    mfma_row(r);
    if (r < 3) commit((r + 3) & 3, (r + 2) % 3);
    __syncthreads();
  }
}

extern "C" void kernel_launch(void* const* d_in, const int* in_sizes, int n_in,
                              void* d_out, int out_size, void* d_ws, size_t ws_size,
                              hipStream_t stream) {
  const float* x = (const float*)d_in[0];
  const float* guide = (const float*)d_in[1];
  const float* weight = (const float*)d_in[2];
  const float* bias = (const float*)d_in[3];
  float* out = (float*)d_out;
  unsigned short* wb = (unsigned short*)d_ws;  // 73728 bytes

  hipLaunchKernelGGL(prep_w, dim3(36864 / 256), dim3(256), 0, stream, weight, wb);
  hipLaunchKernelGGL(pac_main, dim3(256), dim3(512), 0, stream,
                     x, guide, wb, bias, out);
}